// Round 4
// baseline (944.988 us; speedup 1.0000x reference)
//
#include <hip/hip_runtime.h>

#define N_NODES 100000
#define N_EDGES 3200000
#define IN_DIM  29
#define PAD_DIM 32
#define HID_DIM 64
#define NBUCK   391            // ceil(N / 256)
#define BNODES  256            // dst nodes per bucket
#define CAP     10240          // slots per bucket; mean 8192, sigma ~90 -> +22 sigma
#define EPT     16
#define EPB     4096           // 256 threads * 16 edges

// ---- ws layout (4-byte units) ---------------------------------------------
#define OFF_CUR   0            // gcursor[NBUCK]
#define OFF_DINV  512          // dinv[N]
#define OFF_ZS    100608       // zs[2N]
#define OFF_EBUF  300672       // ebuf[NBUCK*CAP] = 4,003,840
#define OFF_XS    4304512      // xs[32N] (128B aligned)
// total 7,504,512 * 4B = 30.0 MB

// ---------------- init: bucket cursors to region starts ---------------------
__global__ void init_kernel(int* __restrict__ gcursor) {
    int b = blockIdx.x * blockDim.x + threadIdx.x;
    if (b < NBUCK) gcursor[b] = b * CAP;
}

// ---------------- partition: bucket edges by dst>>8, packed src|dl ----------
__global__ __launch_bounds__(256) void partition_kernel(const int* __restrict__ ei,
        int* __restrict__ gcursor, int* __restrict__ ebuf) {
    __shared__ int lhist[NBUCK];
    __shared__ int lcur[NBUCK];
    int tid = threadIdx.x;
    for (int i = tid; i < NBUCK; i += 256) lhist[i] = 0;
    __syncthreads();

    int base = blockIdx.x * EPB + tid * EPT;     // 16-aligned; never straddles E
    int dv[EPT], sv[EPT];
    bool valid = (base < N_EDGES);
    if (valid) {
        const int4* dp = (const int4*)(ei + N_EDGES + base);
        const int4* sp = (const int4*)(ei + base);
        #pragma unroll
        for (int q = 0; q < 4; ++q) {
            int4 t = dp[q];
            dv[4*q+0] = t.x; dv[4*q+1] = t.y; dv[4*q+2] = t.z; dv[4*q+3] = t.w;
            int4 u = sp[q];
            sv[4*q+0] = u.x; sv[4*q+1] = u.y; sv[4*q+2] = u.z; sv[4*q+3] = u.w;
        }
        #pragma unroll
        for (int j = 0; j < EPT; ++j) atomicAdd(&lhist[dv[j] >> 8], 1);
    }
    __syncthreads();
    for (int i = tid; i < NBUCK; i += 256) {
        int c = lhist[i];
        lcur[i] = c ? atomicAdd(&gcursor[i], c) : 0;   // block-local base claim
    }
    __syncthreads();
    if (valid) {
        #pragma unroll
        for (int j = 0; j < EPT; ++j) {
            int d = dv[j];
            int pos = atomicAdd(&lcur[d >> 8], 1);     // LDS cursor
            ebuf[pos] = sv[j] | ((d & 255) << 17);     // src < 2^17
        }
    }
}

// ------- per-bucket degree count -> dinv, and xs = x*dinv padded to 32 ------
__global__ __launch_bounds__(256) void degxs_kernel(const int* __restrict__ gcursor,
        const int* __restrict__ ebuf, const float* __restrict__ x,
        float* __restrict__ dinv, float* __restrict__ xs) {
    __shared__ int   cnt[BNODES];
    __shared__ float dls[BNODES];
    int b = blockIdx.x, tid = threadIdx.x;
    cnt[tid] = 0;
    __syncthreads();
    int start = b * CAP, end = gcursor[b];
    for (int j = start + tid; j < end; j += 256)
        atomicAdd(&cnt[((unsigned)ebuf[j]) >> 17], 1);
    __syncthreads();
    int node = b * BNODES + tid;
    if (node < N_NODES) {
        float dn = rsqrtf((float)cnt[tid] + 1.0f);     // +1 = self loop
        dinv[node] = dn;
        dls[tid] = dn;
    }
    __syncthreads();
    for (int i = tid; i < BNODES * PAD_DIM; i += 256) {
        int dl = i >> 5, k = i & 31;
        int nd = b * BNODES + dl;
        if (nd >= N_NODES) break;
        xs[(size_t)b * (BNODES * PAD_DIM) + i] =
            (k < IN_DIM) ? x[nd * IN_DIM + k] * dls[dl] : 0.0f;
    }
}

// ------- agg1: LDS-tile aggregation of xs + fused W1/relu/W2 -> zs ----------
__global__ __launch_bounds__(256) void agg1_kernel(const int* __restrict__ gcursor,
        const int* __restrict__ ebuf, const float* __restrict__ xs,
        const float* __restrict__ dinv,
        const float* __restrict__ W1, const float* __restrict__ b1,
        const float* __restrict__ W2, float* __restrict__ zs) {
    __shared__ float agg[BNODES * PAD_DIM];            // 32 KB
    __shared__ float w1s[IN_DIM * HID_DIM];            // 7.25 KB
    __shared__ float b1s[HID_DIM];
    __shared__ float w2s[HID_DIM * 2];
    int tid = threadIdx.x, b = blockIdx.x;
    for (int i = tid; i < BNODES * PAD_DIM; i += 256) agg[i] = 0.0f;
    for (int i = tid; i < IN_DIM * HID_DIM; i += 256) w1s[i] = W1[i];
    if (tid < HID_DIM) {
        b1s[tid] = b1[tid];
        w2s[tid * 2 + 0] = W2[tid * 2 + 0];
        w2s[tid * 2 + 1] = W2[tid * 2 + 1];
    }
    __syncthreads();

    int start = b * CAP, end = gcursor[b];
    int hw = tid >> 5, k = tid & 31;                   // 8 half-wave edge streams
    for (int j = start + hw; j < end; j += 8) {
        unsigned p = (unsigned)ebuf[j];
        int s  = p & 0x1FFFF;
        int dl = p >> 17;
        atomicAdd(&agg[dl * PAD_DIM + k], xs[(size_t)s * PAD_DIM + k]);
    }
    __syncthreads();

    int wave = tid >> 6, lane = tid & 63;
    for (int dl = wave; dl < BNODES; dl += 4) {
        int node = b * BNODES + dl;
        if (node >= N_NODES) break;
        float dn = dinv[node];
        int kk = lane & 31;
        float acc = (agg[dl * PAD_DIM + kk] + xs[(size_t)node * PAD_DIM + kk]) * dn;
        float h = b1s[lane];
        #pragma unroll
        for (int k2 = 0; k2 < IN_DIM; ++k2)
            h = fmaf(__shfl(acc, k2), w1s[k2 * HID_DIM + lane], h);
        h = fmaxf(h, 0.0f);
        float z0 = h * w2s[lane * 2 + 0];
        float z1 = h * w2s[lane * 2 + 1];
        #pragma unroll
        for (int off = 32; off > 0; off >>= 1) {
            z0 += __shfl_down(z0, off);
            z1 += __shfl_down(z1, off);
        }
        if (lane == 0) {                               // pre-scale by src dinv
            zs[node * 2 + 0] = z0 * dn;
            zs[node * 2 + 1] = z1 * dn;
        }
    }
}

// ------- agg2: LDS-tile aggregation of zs + finalize ------------------------
__global__ __launch_bounds__(256) void agg2_kernel(const int* __restrict__ gcursor,
        const int* __restrict__ ebuf, const float* __restrict__ zs,
        const float* __restrict__ dinv, const float* __restrict__ b2,
        float* __restrict__ out) {
    __shared__ float aggz[BNODES * 2];
    int tid = threadIdx.x, b = blockIdx.x;
    aggz[tid] = 0.0f; aggz[tid + 256] = 0.0f;
    __syncthreads();
    int start = b * CAP, end = gcursor[b];
    for (int j = start + tid; j < end; j += 256) {
        unsigned p = (unsigned)ebuf[j];
        int s  = p & 0x1FFFF;
        int dl = p >> 17;
        float2 zv = *(const float2*)(zs + (size_t)s * 2);
        atomicAdd(&aggz[dl * 2 + 0], zv.x);
        atomicAdd(&aggz[dl * 2 + 1], zv.y);
    }
    __syncthreads();
    int node = b * BNODES + tid;
    if (node < N_NODES) {
        float dn = dinv[node];
        float2 zself = *(const float2*)(zs + (size_t)node * 2);
        float2 o;
        o.x = dn * (aggz[tid * 2 + 0] + zself.x) + b2[0];
        o.y = dn * (aggz[tid * 2 + 1] + zself.y) + b2[1];
        *(float2*)(out + (size_t)node * 2) = o;
    }
}

extern "C" void kernel_launch(void* const* d_in, const int* in_sizes, int n_in,
                              void* d_out, int out_size, void* d_ws, size_t ws_size,
                              hipStream_t stream) {
    const float* x  = (const float*)d_in[0];
    const int*   ei = (const int*)d_in[1];
    const float* W1 = (const float*)d_in[2];
    const float* b1 = (const float*)d_in[3];
    const float* W2 = (const float*)d_in[4];
    const float* b2 = (const float*)d_in[5];
    float* out = (float*)d_out;

    int*   wsi     = (int*)d_ws;
    float* wsf     = (float*)d_ws;
    int*   gcursor = wsi + OFF_CUR;
    float* dinv    = wsf + OFF_DINV;
    float* zs      = wsf + OFF_ZS;
    int*   ebuf    = wsi + OFF_EBUF;
    float* xs      = wsf + OFF_XS;

    init_kernel<<<(NBUCK + 255) / 256, 256, 0, stream>>>(gcursor);
    partition_kernel<<<(N_EDGES + EPB - 1) / EPB, 256, 0, stream>>>(ei, gcursor, ebuf);
    degxs_kernel<<<NBUCK, 256, 0, stream>>>(gcursor, ebuf, x, dinv, xs);
    agg1_kernel<<<NBUCK, 256, 0, stream>>>(gcursor, ebuf, xs, dinv, W1, b1, W2, zs);
    agg2_kernel<<<NBUCK, 256, 0, stream>>>(gcursor, ebuf, zs, dinv, b2, out);
}

// Round 5
// 291.232 us; speedup vs baseline: 3.2448x; 3.2448x over previous
//
#include <hip/hip_runtime.h>

#define N_NODES 100000
#define N_EDGES 3200000
#define IN_DIM  29
#define PAD_DIM 32
#define HID_DIM 64
#define NBUCK   391            // ceil(N / 256)
#define BNODES  256            // dst nodes per bucket
#define CAP     10240          // slots/bucket; mean 8192, sigma ~90 -> +22 sigma
#define EPT     16
#define EPB     4096           // 256 threads * 16 edges

// ---- ws layout (4-byte units) ---------------------------------------------
#define OFF_CUR   0            // gcursor[NBUCK]
#define OFF_ROWS  512          // rowStart[N]
#define OFF_ROWE  100512       // rowEnd[N]
#define OFF_DINV  200512       // dinv[N]
#define OFF_ZS    300512       // zs[2N]
#define OFF_EBUF  500512       // ebuf[NBUCK*CAP] = 4,003,840
#define OFF_XS    4504352      // xs[32N], 128B aligned
// total 7,704,352 * 4B = 30.8 MB

// ---------------- init: bucket cursors to region starts ---------------------
__global__ void init_kernel(int* __restrict__ gcursor) {
    int b = blockIdx.x * blockDim.x + threadIdx.x;
    if (b < NBUCK) gcursor[b] = b * CAP;
}

// ---------------- partition: bucket edges by dst>>8, packed src|dl<<17 ------
__global__ __launch_bounds__(256) void partition_kernel(const int* __restrict__ ei,
        int* __restrict__ gcursor, int* __restrict__ ebuf) {
    __shared__ int lhist[NBUCK];
    __shared__ int lcur[NBUCK];
    int tid = threadIdx.x;
    for (int i = tid; i < NBUCK; i += 256) lhist[i] = 0;
    __syncthreads();

    int base = blockIdx.x * EPB + tid * EPT;     // 16-aligned; never straddles E
    int dv[EPT], sv[EPT];
    bool valid = (base < N_EDGES);
    if (valid) {
        const int4* dp = (const int4*)(ei + N_EDGES + base);
        const int4* sp = (const int4*)(ei + base);
        #pragma unroll
        for (int q = 0; q < 4; ++q) {
            int4 t = dp[q];
            dv[4*q+0] = t.x; dv[4*q+1] = t.y; dv[4*q+2] = t.z; dv[4*q+3] = t.w;
            int4 u = sp[q];
            sv[4*q+0] = u.x; sv[4*q+1] = u.y; sv[4*q+2] = u.z; sv[4*q+3] = u.w;
        }
        #pragma unroll
        for (int j = 0; j < EPT; ++j) atomicAdd(&lhist[dv[j] >> 8], 1);
    }
    __syncthreads();
    for (int i = tid; i < NBUCK; i += 256) {
        int c = lhist[i];
        lcur[i] = c ? atomicAdd(&gcursor[i], c) : 0;   // block-local base claim
    }
    __syncthreads();
    if (valid) {
        #pragma unroll
        for (int j = 0; j < EPT; ++j) {
            int d = dv[j];
            int pos = atomicAdd(&lcur[d >> 8], 1);     // LDS cursor
            ebuf[pos] = sv[j] | ((d & 255) << 17);     // src < 2^17
        }
    }
}

// ---- per-bucket exact counting sort in LDS + rowStart/rowEnd/dinv/xs -------
__global__ __launch_bounds__(256) void bucketsort_kernel(const int* __restrict__ gcursor,
        int* __restrict__ ebuf, int* __restrict__ rowStart, int* __restrict__ rowEnd,
        float* __restrict__ dinv, const float* __restrict__ x, float* __restrict__ xs) {
    __shared__ int   cnt[BNODES];
    __shared__ int   cur[BNODES];
    __shared__ float dls[BNODES];
    __shared__ int   stage[CAP];                       // 40 KB
    int b = blockIdx.x, tid = threadIdx.x;
    cnt[tid] = 0;
    __syncthreads();
    int base = b * CAP;
    int size = gcursor[b] - base;

    for (int j = tid; j < size; j += 256)              // pass 1: count
        atomicAdd(&cnt[((unsigned)ebuf[base + j]) >> 17], 1);
    __syncthreads();

    int v = cnt[tid];                                  // inclusive scan in cur
    cur[tid] = v;
    __syncthreads();
    for (int off = 1; off < 256; off <<= 1) {
        int t = (tid >= off) ? cur[tid - off] : 0;
        __syncthreads();
        cur[tid] += t;
        __syncthreads();
    }
    int excl = cur[tid] - v;

    int node = b * BNODES + tid;
    if (node < N_NODES) {
        rowStart[node] = base + excl;
        rowEnd[node]   = base + excl + v;
        float dn = rsqrtf((float)v + 1.0f);            // +1 = self loop
        dinv[node] = dn;
        dls[tid] = dn;
    }
    __syncthreads();
    cur[tid] = excl;                                   // becomes cursor
    __syncthreads();

    for (int j = tid; j < size; j += 256) {            // pass 2: place into LDS
        unsigned p = (unsigned)ebuf[base + j];
        int pos = atomicAdd(&cur[p >> 17], 1);
        stage[pos] = p & 0x1FFFF;
    }
    __syncthreads();
    for (int j = tid; j < size; j += 256)              // coalesced writeback
        ebuf[base + j] = stage[j];

    // xs = x * dinv, padded to 32 floats/node (this block owns these nodes)
    for (int i = tid; i < BNODES * PAD_DIM; i += 256) {
        int dl = i >> 5, k = i & 31;
        int nd = b * BNODES + dl;
        if (nd < N_NODES)
            xs[(size_t)b * (BNODES * PAD_DIM) + i] =
                (k < IN_DIM) ? x[nd * IN_DIM + k] * dls[dl] : 0.0f;
    }
}

// ------- fused: per-node gather (4 quarter-wave streams) + W1/relu/W2 -------
__global__ __launch_bounds__(256) void fused_kernel(const float* __restrict__ xs,
        const int* __restrict__ rowStart, const int* __restrict__ rowEnd,
        const int* __restrict__ ebuf, const float* __restrict__ dinv,
        const float* __restrict__ W1, const float* __restrict__ b1,
        const float* __restrict__ W2, float* __restrict__ zs) {
    __shared__ float w1s[IN_DIM * HID_DIM];
    __shared__ float b1s[HID_DIM];
    __shared__ float w2s[HID_DIM * 2];
    int tid = threadIdx.x;
    for (int i = tid; i < IN_DIM * HID_DIM; i += 256) w1s[i] = W1[i];
    if (tid < HID_DIM) {
        b1s[tid] = b1[tid];
        w2s[tid * 2 + 0] = W2[tid * 2 + 0];
        w2s[tid * 2 + 1] = W2[tid * 2 + 1];
    }
    __syncthreads();

    int lane = tid & 63;
    int node = blockIdx.x * 4 + (tid >> 6);
    if (node >= N_NODES) return;

    int q = lane >> 4, m = lane & 15;                  // quarter-wave streams
    const float2* xs2 = (const float2*)xs;
    float2 acc = (q == 0) ? xs2[(size_t)node * 16 + m] // self loop in stream 0
                          : make_float2(0.0f, 0.0f);
    int rs = rowStart[node], re = rowEnd[node];
    for (int j = rs + q; j < re; j += 4) {
        int s = ebuf[j];
        float2 t = xs2[(size_t)s * 16 + m];            // 128B line per edge
        acc.x += t.x; acc.y += t.y;
    }
    acc.x += __shfl_xor(acc.x, 16); acc.y += __shfl_xor(acc.y, 16);
    acc.x += __shfl_xor(acc.x, 32); acc.y += __shfl_xor(acc.y, 32);
    float dn = dinv[node];
    acc.x *= dn; acc.y *= dn;

    float h = b1s[lane];
    #pragma unroll
    for (int kk = 0; kk < IN_DIM; ++kk) {
        float a = __shfl((kk & 1) ? acc.y : acc.x, kk >> 1);  // compile-time pick
        h = fmaf(a, w1s[kk * HID_DIM + lane], h);
    }
    h = fmaxf(h, 0.0f);

    float z0 = h * w2s[lane * 2 + 0];
    float z1 = h * w2s[lane * 2 + 1];
    #pragma unroll
    for (int off = 32; off > 0; off >>= 1) {
        z0 += __shfl_down(z0, off);
        z1 += __shfl_down(z1, off);
    }
    if (lane == 0) {                                   // pre-scale by src dinv
        zs[node * 2 + 0] = z0 * dn;
        zs[node * 2 + 1] = z1 * dn;
    }
}

// ------- agg2: 16-lane group per node gathers zs + finalize -----------------
__global__ __launch_bounds__(256) void agg2_kernel(const float* __restrict__ zs,
        const int* __restrict__ rowStart, const int* __restrict__ rowEnd,
        const int* __restrict__ ebuf, const float* __restrict__ dinv,
        const float* __restrict__ b2, float* __restrict__ out) {
    int tid = threadIdx.x;
    int node = blockIdx.x * 16 + (tid >> 4);
    if (node >= N_NODES) return;
    int gl = tid & 15;
    const float2* zs2 = (const float2*)zs;
    float a0 = 0.0f, a1 = 0.0f;
    int rs = rowStart[node], re = rowEnd[node];
    for (int j = rs + gl; j < re; j += 16) {
        float2 zv = zs2[ebuf[j]];
        a0 += zv.x; a1 += zv.y;
    }
    a0 += __shfl_xor(a0, 8); a1 += __shfl_xor(a1, 8);
    a0 += __shfl_xor(a0, 4); a1 += __shfl_xor(a1, 4);
    a0 += __shfl_xor(a0, 2); a1 += __shfl_xor(a1, 2);
    a0 += __shfl_xor(a0, 1); a1 += __shfl_xor(a1, 1);
    if (gl == 0) {
        float dn = dinv[node];
        float2 zself = zs2[node];
        float2 o;
        o.x = dn * (a0 + zself.x) + b2[0];
        o.y = dn * (a1 + zself.y) + b2[1];
        ((float2*)out)[node] = o;
    }
}

extern "C" void kernel_launch(void* const* d_in, const int* in_sizes, int n_in,
                              void* d_out, int out_size, void* d_ws, size_t ws_size,
                              hipStream_t stream) {
    const float* x  = (const float*)d_in[0];
    const int*   ei = (const int*)d_in[1];
    const float* W1 = (const float*)d_in[2];
    const float* b1 = (const float*)d_in[3];
    const float* W2 = (const float*)d_in[4];
    const float* b2 = (const float*)d_in[5];
    float* out = (float*)d_out;

    int*   wsi      = (int*)d_ws;
    float* wsf      = (float*)d_ws;
    int*   gcursor  = wsi + OFF_CUR;
    int*   rowStart = wsi + OFF_ROWS;
    int*   rowEnd   = wsi + OFF_ROWE;
    float* dinv     = wsf + OFF_DINV;
    float* zs       = wsf + OFF_ZS;
    int*   ebuf     = wsi + OFF_EBUF;
    float* xs       = wsf + OFF_XS;

    init_kernel<<<(NBUCK + 255) / 256, 256, 0, stream>>>(gcursor);
    partition_kernel<<<(N_EDGES + EPB - 1) / EPB, 256, 0, stream>>>(ei, gcursor, ebuf);
    bucketsort_kernel<<<NBUCK, 256, 0, stream>>>(gcursor, ebuf, rowStart, rowEnd, dinv, x, xs);
    fused_kernel<<<(N_NODES + 3) / 4, 256, 0, stream>>>(xs, rowStart, rowEnd, ebuf, dinv, W1, b1, W2, zs);
    agg2_kernel<<<(N_NODES + 15) / 16, 256, 0, stream>>>(zs, rowStart, rowEnd, ebuf, dinv, b2, out);
}

// Round 6
// 262.368 us; speedup vs baseline: 3.6018x; 1.1100x over previous
//
#include <hip/hip_runtime.h>

#define N_NODES 100000
#define N_EDGES 3200000
#define IN_DIM  29
#define PAD_DIM 32
#define HID_DIM 64
#define NBUCK   391            // ceil(N / 256)
#define BNODES  256            // dst nodes per bucket
#define CAP     10240          // slots/bucket; mean 8192, sigma ~90 -> +22 sigma
#define EPT     16
#define EPB     4096           // 256 threads * 16 edges

// ---- ws layout (4-byte units) ---------------------------------------------
#define OFF_CUR   0            // gcursor[NBUCK]
#define OFF_ROWS  512          // rowStart[N]
#define OFF_ROWE  100512       // rowEnd[N]
#define OFF_DINV  200512       // dinv[N]
#define OFF_ZS    300512       // zs[2N]
#define OFF_EBUF  500512       // ebuf[NBUCK*CAP] = 4,003,840
#define OFF_XS    4504352      // xs bf16[32N] = 16N uints, 128B aligned

static __device__ __forceinline__ unsigned short f2bf(float f) {
    unsigned u = __float_as_uint(f);
    u += 0x7fffu + ((u >> 16) & 1u);   // RNE
    return (unsigned short)(u >> 16);
}

// ---------------- init: bucket cursors to region starts ---------------------
__global__ void init_kernel(int* __restrict__ gcursor) {
    int b = blockIdx.x * blockDim.x + threadIdx.x;
    if (b < NBUCK) gcursor[b] = b * CAP;
}

// ---------------- partition: bucket edges by dst>>8, packed src|dl<<17 ------
__global__ __launch_bounds__(256) void partition_kernel(const int* __restrict__ ei,
        int* __restrict__ gcursor, int* __restrict__ ebuf) {
    __shared__ int lhist[NBUCK];
    __shared__ int lcur[NBUCK];
    int tid = threadIdx.x;
    for (int i = tid; i < NBUCK; i += 256) lhist[i] = 0;
    __syncthreads();

    int base = blockIdx.x * EPB + tid * EPT;     // 16-aligned; never straddles E
    int dv[EPT], sv[EPT];
    bool valid = (base < N_EDGES);
    if (valid) {
        const int4* dp = (const int4*)(ei + N_EDGES + base);
        const int4* sp = (const int4*)(ei + base);
        #pragma unroll
        for (int q = 0; q < 4; ++q) {
            int4 t = dp[q];
            dv[4*q+0] = t.x; dv[4*q+1] = t.y; dv[4*q+2] = t.z; dv[4*q+3] = t.w;
            int4 u = sp[q];
            sv[4*q+0] = u.x; sv[4*q+1] = u.y; sv[4*q+2] = u.z; sv[4*q+3] = u.w;
        }
        #pragma unroll
        for (int j = 0; j < EPT; ++j) atomicAdd(&lhist[dv[j] >> 8], 1);
    }
    __syncthreads();
    for (int i = tid; i < NBUCK; i += 256) {
        int c = lhist[i];
        lcur[i] = c ? atomicAdd(&gcursor[i], c) : 0;   // block-local base claim
    }
    __syncthreads();
    if (valid) {
        #pragma unroll
        for (int j = 0; j < EPT; ++j) {
            int d = dv[j];
            int pos = atomicAdd(&lcur[d >> 8], 1);     // LDS cursor
            ebuf[pos] = sv[j] | ((d & 255) << 17);     // src < 2^17
        }
    }
}

// ---- per-bucket exact counting sort in LDS + rowStart/rowEnd/dinv/xs -------
__global__ __launch_bounds__(256) void bucketsort_kernel(const int* __restrict__ gcursor,
        int* __restrict__ ebuf, int* __restrict__ rowStart, int* __restrict__ rowEnd,
        float* __restrict__ dinv, const float* __restrict__ x,
        unsigned int* __restrict__ xsb) {
    __shared__ int   cnt[BNODES];
    __shared__ int   cur[BNODES];
    __shared__ float dls[BNODES];
    __shared__ int   stage[CAP];                       // 40 KB
    int b = blockIdx.x, tid = threadIdx.x;
    cnt[tid] = 0;
    __syncthreads();
    int base = b * CAP;
    int size = gcursor[b] - base;

    for (int j = tid; j < size; j += 256)              // pass 1: count
        atomicAdd(&cnt[((unsigned)ebuf[base + j]) >> 17], 1);
    __syncthreads();

    int v = cnt[tid];                                  // inclusive scan in cur
    cur[tid] = v;
    __syncthreads();
    for (int off = 1; off < 256; off <<= 1) {
        int t = (tid >= off) ? cur[tid - off] : 0;
        __syncthreads();
        cur[tid] += t;
        __syncthreads();
    }
    int excl = cur[tid] - v;

    int node = b * BNODES + tid;
    if (node < N_NODES) {
        rowStart[node] = base + excl;
        rowEnd[node]   = base + excl + v;
        float dn = rsqrtf((float)v + 1.0f);            // +1 = self loop
        dinv[node] = dn;
        dls[tid] = dn;
    }
    __syncthreads();
    cur[tid] = excl;                                   // becomes cursor
    __syncthreads();

    for (int j = tid; j < size; j += 256) {            // pass 2: place into LDS
        unsigned p = (unsigned)ebuf[base + j];
        int pos = atomicAdd(&cur[p >> 17], 1);
        stage[pos] = p & 0x1FFFF;
    }
    __syncthreads();
    for (int j = tid; j < size; j += 256)              // coalesced writeback
        ebuf[base + j] = stage[j];

    // xs = bf16(x * dinv), padded to 32 features; 2 features per uint
    for (int i = tid; i < BNODES * 16; i += 256) {
        int dl = i >> 4, kp = i & 15;                  // features 2kp, 2kp+1
        int nd = b * BNODES + dl;
        if (nd < N_NODES) {
            float dn = dls[dl];
            int k0 = kp * 2, k1 = k0 + 1;
            float f0 = (k0 < IN_DIM) ? x[nd * IN_DIM + k0] * dn : 0.0f;
            float f1 = (k1 < IN_DIM) ? x[nd * IN_DIM + k1] * dn : 0.0f;
            unsigned u = (unsigned)f2bf(f0) | ((unsigned)f2bf(f1) << 16);
            xsb[(size_t)nd * 16 + kp] = u;
        }
    }
}

// ------- fused: per-node gather (8 streams, bf16, 2x unroll) + W1/relu/W2 ---
__global__ __launch_bounds__(256) void fused_kernel(const unsigned int* __restrict__ xs_,
        const int* __restrict__ rowStart, const int* __restrict__ rowEnd,
        const int* __restrict__ ebuf, const float* __restrict__ dinv,
        const float* __restrict__ W1, const float* __restrict__ b1,
        const float* __restrict__ W2, float* __restrict__ zs) {
    __shared__ float w1s[IN_DIM * HID_DIM];
    __shared__ float b1s[HID_DIM];
    __shared__ float w2s[HID_DIM * 2];
    int tid = threadIdx.x;
    for (int i = tid; i < IN_DIM * HID_DIM; i += 256) w1s[i] = W1[i];
    if (tid < HID_DIM) {
        b1s[tid] = b1[tid];
        w2s[tid * 2 + 0] = W2[tid * 2 + 0];
        w2s[tid * 2 + 1] = W2[tid * 2 + 1];
    }
    __syncthreads();

    int lane = tid & 63;
    int node = blockIdx.x * 4 + (tid >> 6);
    if (node >= N_NODES) return;

    const uint2* xsb = (const uint2*)xs_;              // row = 8 uint2 (64 B)
    int q = lane >> 3, m = lane & 7;                   // 8 streams x 8 lanes

    float4 acc0 = make_float4(0.f, 0.f, 0.f, 0.f);
    float4 acc1 = make_float4(0.f, 0.f, 0.f, 0.f);
    if (q == 0) {                                      // self loop once
        uint2 a = xsb[(size_t)node * 8 + m];
        acc0.x = __uint_as_float(a.x << 16);
        acc0.y = __uint_as_float(a.x & 0xFFFF0000u);
        acc0.z = __uint_as_float(a.y << 16);
        acc0.w = __uint_as_float(a.y & 0xFFFF0000u);
    }

    int rs = rowStart[node], re = rowEnd[node];
    int j = rs + q;
    for (; j + 8 < re; j += 16) {                      // 2 independent gathers
        int s0 = ebuf[j];
        int s1 = ebuf[j + 8];
        uint2 a = xsb[(size_t)s0 * 8 + m];
        uint2 c = xsb[(size_t)s1 * 8 + m];
        acc0.x += __uint_as_float(a.x << 16);
        acc0.y += __uint_as_float(a.x & 0xFFFF0000u);
        acc0.z += __uint_as_float(a.y << 16);
        acc0.w += __uint_as_float(a.y & 0xFFFF0000u);
        acc1.x += __uint_as_float(c.x << 16);
        acc1.y += __uint_as_float(c.x & 0xFFFF0000u);
        acc1.z += __uint_as_float(c.y << 16);
        acc1.w += __uint_as_float(c.y & 0xFFFF0000u);
    }
    if (j < re) {
        int s0 = ebuf[j];
        uint2 a = xsb[(size_t)s0 * 8 + m];
        acc0.x += __uint_as_float(a.x << 16);
        acc0.y += __uint_as_float(a.x & 0xFFFF0000u);
        acc0.z += __uint_as_float(a.y << 16);
        acc0.w += __uint_as_float(a.y & 0xFFFF0000u);
    }
    acc0.x += acc1.x; acc0.y += acc1.y; acc0.z += acc1.z; acc0.w += acc1.w;
    #pragma unroll
    for (int msk = 8; msk <= 32; msk <<= 1) {          // fold 8 streams
        acc0.x += __shfl_xor(acc0.x, msk);
        acc0.y += __shfl_xor(acc0.y, msk);
        acc0.z += __shfl_xor(acc0.z, msk);
        acc0.w += __shfl_xor(acc0.w, msk);
    }
    float dn = dinv[node];
    acc0.x *= dn; acc0.y *= dn; acc0.z *= dn; acc0.w *= dn;

    float h = b1s[lane];
    #pragma unroll
    for (int kk = 0; kk < IN_DIM; ++kk) {              // comp pick is compile-time
        float comp = ((kk & 3) == 0) ? acc0.x : ((kk & 3) == 1) ? acc0.y
                   : ((kk & 3) == 2) ? acc0.z : acc0.w;
        h = fmaf(__shfl(comp, kk >> 2), w1s[kk * HID_DIM + lane], h);
    }
    h = fmaxf(h, 0.0f);

    float z0 = h * w2s[lane * 2 + 0];
    float z1 = h * w2s[lane * 2 + 1];
    #pragma unroll
    for (int off = 32; off > 0; off >>= 1) {
        z0 += __shfl_down(z0, off);
        z1 += __shfl_down(z1, off);
    }
    if (lane == 0) {                                   // pre-scale by src dinv
        zs[node * 2 + 0] = z0 * dn;
        zs[node * 2 + 1] = z1 * dn;
    }
}

// ------- agg2: 16-lane group per node gathers zs (2x unroll) + finalize -----
__global__ __launch_bounds__(256) void agg2_kernel(const float* __restrict__ zs,
        const int* __restrict__ rowStart, const int* __restrict__ rowEnd,
        const int* __restrict__ ebuf, const float* __restrict__ dinv,
        const float* __restrict__ b2, float* __restrict__ out) {
    int tid = threadIdx.x;
    int node = blockIdx.x * 16 + (tid >> 4);
    if (node >= N_NODES) return;
    int gl = tid & 15;
    const float2* zs2 = (const float2*)zs;
    float a0 = 0.0f, a1 = 0.0f, c0 = 0.0f, c1 = 0.0f;
    int rs = rowStart[node], re = rowEnd[node];
    int j = rs + gl;
    for (; j + 16 < re; j += 32) {
        float2 za = zs2[ebuf[j]];
        float2 zb = zs2[ebuf[j + 16]];
        a0 += za.x; a1 += za.y;
        c0 += zb.x; c1 += zb.y;
    }
    if (j < re) {
        float2 za = zs2[ebuf[j]];
        a0 += za.x; a1 += za.y;
    }
    a0 += c0; a1 += c1;
    a0 += __shfl_xor(a0, 8); a1 += __shfl_xor(a1, 8);
    a0 += __shfl_xor(a0, 4); a1 += __shfl_xor(a1, 4);
    a0 += __shfl_xor(a0, 2); a1 += __shfl_xor(a1, 2);
    a0 += __shfl_xor(a0, 1); a1 += __shfl_xor(a1, 1);
    if (gl == 0) {
        float dn = dinv[node];
        float2 zself = zs2[node];
        float2 o;
        o.x = dn * (a0 + zself.x) + b2[0];
        o.y = dn * (a1 + zself.y) + b2[1];
        ((float2*)out)[node] = o;
    }
}

extern "C" void kernel_launch(void* const* d_in, const int* in_sizes, int n_in,
                              void* d_out, int out_size, void* d_ws, size_t ws_size,
                              hipStream_t stream) {
    const float* x  = (const float*)d_in[0];
    const int*   ei = (const int*)d_in[1];
    const float* W1 = (const float*)d_in[2];
    const float* b1 = (const float*)d_in[3];
    const float* W2 = (const float*)d_in[4];
    const float* b2 = (const float*)d_in[5];
    float* out = (float*)d_out;

    int*   wsi      = (int*)d_ws;
    float* wsf      = (float*)d_ws;
    int*   gcursor  = wsi + OFF_CUR;
    int*   rowStart = wsi + OFF_ROWS;
    int*   rowEnd   = wsi + OFF_ROWE;
    float* dinv     = wsf + OFF_DINV;
    float* zs       = wsf + OFF_ZS;
    int*   ebuf     = wsi + OFF_EBUF;
    unsigned int* xsb = (unsigned int*)(wsi + OFF_XS);

    init_kernel<<<(NBUCK + 255) / 256, 256, 0, stream>>>(gcursor);
    partition_kernel<<<(N_EDGES + EPB - 1) / EPB, 256, 0, stream>>>(ei, gcursor, ebuf);
    bucketsort_kernel<<<NBUCK, 256, 0, stream>>>(gcursor, ebuf, rowStart, rowEnd, dinv, x, xsb);
    fused_kernel<<<(N_NODES + 3) / 4, 256, 0, stream>>>(xsb, rowStart, rowEnd, ebuf, dinv, W1, b1, W2, zs);
    agg2_kernel<<<(N_NODES + 15) / 16, 256, 0, stream>>>(zs, rowStart, rowEnd, ebuf, dinv, b2, out);
}

// Round 7
// 227.123 us; speedup vs baseline: 4.1607x; 1.1552x over previous
//
#include <hip/hip_runtime.h>

#define N_NODES 100000
#define N_EDGES 3200000
#define IN_DIM  29
#define HID_DIM 64
#define NBUCK   391            // ceil(N / 256)
#define BNODES  256            // dst nodes per bucket
#define CAP     10240          // slots/bucket; mean 8189, sigma ~90 -> +22 sigma
#define EPT     8
#define EPB     4096           // 512 threads * 8 edges

// ---- ws layout (4-byte units) ---------------------------------------------
#define OFF_CUR   0            // gcursor[NBUCK] (sizes; region b starts at b*CAP)
#define OFF_ROWS  512          // rowStart[N]
#define OFF_ROWE  100512       // rowEnd[N]
#define OFF_DINV  200512       // dinv[N]
#define OFF_ZS    300512       // zs[2N]
#define OFF_EBUF  500512       // ebuf[NBUCK*CAP] = 4,003,840
#define OFF_XS    4504352      // xs bf16[32N] = 16N uints, 128B aligned

static __device__ __forceinline__ unsigned short f2bf(float f) {
    unsigned u = __float_as_uint(f);
    u += 0x7fffu + ((u >> 16) & 1u);   // RNE
    return (unsigned short)(u >> 16);
}

static __device__ __forceinline__ void unpack_add(float4& acc, uint2 a) {
    acc.x += __uint_as_float(a.x << 16);
    acc.y += __uint_as_float(a.x & 0xFFFF0000u);
    acc.z += __uint_as_float(a.y << 16);
    acc.w += __uint_as_float(a.y & 0xFFFF0000u);
}

// ---------------- partition: bucket edges by dst>>8, packed src|dl<<17 ------
__global__ __launch_bounds__(512) void partition_kernel(const int* __restrict__ ei,
        int* __restrict__ gcursor, int* __restrict__ ebuf) {
    __shared__ int lhist[NBUCK];
    __shared__ int lcur[NBUCK];
    int tid = threadIdx.x;
    for (int i = tid; i < NBUCK; i += 512) lhist[i] = 0;
    __syncthreads();

    int base = blockIdx.x * EPB + tid * EPT;     // 8-aligned; never straddles E
    int dv[EPT], sv[EPT];
    bool valid = (base < N_EDGES);
    if (valid) {
        const int4* dp = (const int4*)(ei + N_EDGES + base);
        const int4* sp = (const int4*)(ei + base);
        #pragma unroll
        for (int q = 0; q < 2; ++q) {
            int4 t = dp[q];
            dv[4*q+0] = t.x; dv[4*q+1] = t.y; dv[4*q+2] = t.z; dv[4*q+3] = t.w;
            int4 u = sp[q];
            sv[4*q+0] = u.x; sv[4*q+1] = u.y; sv[4*q+2] = u.z; sv[4*q+3] = u.w;
        }
        #pragma unroll
        for (int j = 0; j < EPT; ++j) atomicAdd(&lhist[dv[j] >> 8], 1);
    }
    __syncthreads();
    for (int i = tid; i < NBUCK; i += 512) {
        int c = lhist[i];
        lcur[i] = c ? (atomicAdd(&gcursor[i], c) + i * CAP) : 0;  // claim base
    }
    __syncthreads();
    if (valid) {
        #pragma unroll
        for (int j = 0; j < EPT; ++j) {
            int d = dv[j];
            int pos = atomicAdd(&lcur[d >> 8], 1);     // LDS cursor
            ebuf[pos] = sv[j] | ((d & 255) << 17);     // src < 2^17
        }
    }
}

// ---- per-bucket exact counting sort in LDS + rowStart/rowEnd/dinv/xs -------
__global__ __launch_bounds__(1024) void bucketsort_kernel(const int* __restrict__ gcursor,
        int* __restrict__ ebuf, int* __restrict__ rowStart, int* __restrict__ rowEnd,
        float* __restrict__ dinv, const float* __restrict__ x,
        unsigned int* __restrict__ xsb) {
    __shared__ int   cnt[BNODES];
    __shared__ int   cur[BNODES];
    __shared__ float dls[BNODES];
    __shared__ int   stage[CAP];                       // 40 KB
    int b = blockIdx.x, tid = threadIdx.x;
    if (tid < BNODES) cnt[tid] = 0;
    __syncthreads();
    int base = b * CAP;
    int size = gcursor[b];

    for (int j = tid; j < size; j += 1024)             // pass 1: count
        atomicAdd(&cnt[((unsigned)ebuf[base + j]) >> 17], 1);
    __syncthreads();

    int v = 0;
    if (tid < BNODES) { v = cnt[tid]; cur[tid] = v; }  // inclusive scan in cur
    __syncthreads();
    for (int off = 1; off < BNODES; off <<= 1) {
        int t = 0;
        if (tid < BNODES && tid >= off) t = cur[tid - off];
        __syncthreads();
        if (tid < BNODES) cur[tid] += t;
        __syncthreads();
    }
    if (tid < BNODES) {
        int excl = cur[tid] - v;
        int node = b * BNODES + tid;
        if (node < N_NODES) {
            rowStart[node] = base + excl;
            rowEnd[node]   = base + excl + v;
            float dn = rsqrtf((float)v + 1.0f);        // +1 = self loop
            dinv[node] = dn;
            dls[tid] = dn;
        }
        cur[tid] = excl;                               // becomes cursor
    }
    __syncthreads();

    for (int j = tid; j < size; j += 1024) {           // pass 2: place into LDS
        unsigned p = (unsigned)ebuf[base + j];
        int pos = atomicAdd(&cur[p >> 17], 1);
        stage[pos] = p & 0x1FFFF;
    }
    __syncthreads();
    for (int j = tid; j < size; j += 1024)             // coalesced writeback
        ebuf[base + j] = stage[j];

    // xs = bf16(x * dinv), padded to 32 features; 2 features per uint
    for (int i = tid; i < BNODES * 16; i += 1024) {
        int dl = i >> 4, kp = i & 15;                  // features 2kp, 2kp+1
        int nd = b * BNODES + dl;
        if (nd < N_NODES) {
            float dn = dls[dl];
            int k0 = kp * 2, k1 = k0 + 1;
            float f0 = (k0 < IN_DIM) ? x[nd * IN_DIM + k0] * dn : 0.0f;
            float f1 = (k1 < IN_DIM) ? x[nd * IN_DIM + k1] * dn : 0.0f;
            unsigned u = (unsigned)f2bf(f0) | ((unsigned)f2bf(f1) << 16);
            xsb[(size_t)nd * 16 + kp] = u;
        }
    }
}

// --- fused: per-node gather (8 streams, bf16, unroll-4, 4 nodes/wave) -------
__global__ __launch_bounds__(256) void fused_kernel(const unsigned int* __restrict__ xs_,
        const int* __restrict__ rowStart, const int* __restrict__ rowEnd,
        const int* __restrict__ ebuf, const float* __restrict__ dinv,
        const float* __restrict__ W1, const float* __restrict__ b1,
        const float* __restrict__ W2, float* __restrict__ zs) {
    __shared__ float w1s[IN_DIM * HID_DIM];
    __shared__ float b1s[HID_DIM];
    __shared__ float w2s[HID_DIM * 2];
    int tid = threadIdx.x;
    for (int i = tid; i < IN_DIM * HID_DIM; i += 256) w1s[i] = W1[i];
    if (tid < HID_DIM) {
        b1s[tid] = b1[tid];
        w2s[tid * 2 + 0] = W2[tid * 2 + 0];
        w2s[tid * 2 + 1] = W2[tid * 2 + 1];
    }
    __syncthreads();

    int lane = tid & 63;
    int q = lane >> 3, m = lane & 7;                   // 8 streams x 8 lanes
    const uint2* xsb = (const uint2*)xs_;              // row = 8 uint2 (64 B)
    int nodeBase = blockIdx.x * 16 + (tid >> 6) * 4;   // 4 nodes per wave

    for (int rep = 0; rep < 4; ++rep) {
        int node = nodeBase + rep;
        if (node >= N_NODES) break;

        float4 acc = make_float4(0.f, 0.f, 0.f, 0.f);
        if (q == 0)                                    // self loop in stream 0
            unpack_add(acc, xsb[(size_t)node * 8 + m]);

        int rs = rowStart[node], re = rowEnd[node];
        int j = rs + q;
        for (; j + 24 < re; j += 32) {                 // 4 gathers in flight
            int s0 = ebuf[j];
            int s1 = ebuf[j + 8];
            int s2 = ebuf[j + 16];
            int s3 = ebuf[j + 24];
            uint2 a = xsb[(size_t)s0 * 8 + m];
            uint2 bb = xsb[(size_t)s1 * 8 + m];
            uint2 c = xsb[(size_t)s2 * 8 + m];
            uint2 d = xsb[(size_t)s3 * 8 + m];
            unpack_add(acc, a);
            unpack_add(acc, bb);
            unpack_add(acc, c);
            unpack_add(acc, d);
        }
        for (; j < re; j += 8) {                       // remainder (<=3)
            uint2 a = xsb[(size_t)ebuf[j] * 8 + m];
            unpack_add(acc, a);
        }
        #pragma unroll
        for (int msk = 8; msk <= 32; msk <<= 1) {      // fold 8 streams
            acc.x += __shfl_xor(acc.x, msk);
            acc.y += __shfl_xor(acc.y, msk);
            acc.z += __shfl_xor(acc.z, msk);
            acc.w += __shfl_xor(acc.w, msk);
        }
        float dn = dinv[node];
        acc.x *= dn; acc.y *= dn; acc.z *= dn; acc.w *= dn;

        float h = b1s[lane];
        #pragma unroll
        for (int kk = 0; kk < IN_DIM; ++kk) {          // comp pick compile-time
            float comp = ((kk & 3) == 0) ? acc.x : ((kk & 3) == 1) ? acc.y
                       : ((kk & 3) == 2) ? acc.z : acc.w;
            h = fmaf(__shfl(comp, kk >> 2), w1s[kk * HID_DIM + lane], h);
        }
        h = fmaxf(h, 0.0f);

        float z0 = h * w2s[lane * 2 + 0];
        float z1 = h * w2s[lane * 2 + 1];
        #pragma unroll
        for (int off = 32; off > 0; off >>= 1) {
            z0 += __shfl_down(z0, off);
            z1 += __shfl_down(z1, off);
        }
        if (lane == 0) {                               // pre-scale by src dinv
            zs[node * 2 + 0] = z0 * dn;
            zs[node * 2 + 1] = z1 * dn;
        }
    }
}

// ------- agg2: 16-lane group per node gathers zs (2x unroll) + finalize -----
__global__ __launch_bounds__(256) void agg2_kernel(const float* __restrict__ zs,
        const int* __restrict__ rowStart, const int* __restrict__ rowEnd,
        const int* __restrict__ ebuf, const float* __restrict__ dinv,
        const float* __restrict__ b2, float* __restrict__ out) {
    int tid = threadIdx.x;
    int node = blockIdx.x * 16 + (tid >> 4);
    if (node >= N_NODES) return;
    int gl = tid & 15;
    const float2* zs2 = (const float2*)zs;
    float a0 = 0.0f, a1 = 0.0f, c0 = 0.0f, c1 = 0.0f;
    int rs = rowStart[node], re = rowEnd[node];
    int j = rs + gl;
    for (; j + 16 < re; j += 32) {
        float2 za = zs2[ebuf[j]];
        float2 zb = zs2[ebuf[j + 16]];
        a0 += za.x; a1 += za.y;
        c0 += zb.x; c1 += zb.y;
    }
    if (j < re) {
        float2 za = zs2[ebuf[j]];
        a0 += za.x; a1 += za.y;
    }
    a0 += c0; a1 += c1;
    a0 += __shfl_xor(a0, 8); a1 += __shfl_xor(a1, 8);
    a0 += __shfl_xor(a0, 4); a1 += __shfl_xor(a1, 4);
    a0 += __shfl_xor(a0, 2); a1 += __shfl_xor(a1, 2);
    a0 += __shfl_xor(a0, 1); a1 += __shfl_xor(a1, 1);
    if (gl == 0) {
        float dn = dinv[node];
        float2 zself = zs2[node];
        float2 o;
        o.x = dn * (a0 + zself.x) + b2[0];
        o.y = dn * (a1 + zself.y) + b2[1];
        ((float2*)out)[node] = o;
    }
}

extern "C" void kernel_launch(void* const* d_in, const int* in_sizes, int n_in,
                              void* d_out, int out_size, void* d_ws, size_t ws_size,
                              hipStream_t stream) {
    const float* x  = (const float*)d_in[0];
    const int*   ei = (const int*)d_in[1];
    const float* W1 = (const float*)d_in[2];
    const float* b1 = (const float*)d_in[3];
    const float* W2 = (const float*)d_in[4];
    const float* b2 = (const float*)d_in[5];
    float* out = (float*)d_out;

    int*   wsi      = (int*)d_ws;
    float* wsf      = (float*)d_ws;
    int*   gcursor  = wsi + OFF_CUR;
    int*   rowStart = wsi + OFF_ROWS;
    int*   rowEnd   = wsi + OFF_ROWE;
    float* dinv     = wsf + OFF_DINV;
    float* zs       = wsf + OFF_ZS;
    int*   ebuf     = wsi + OFF_EBUF;
    unsigned int* xsb = (unsigned int*)(wsi + OFF_XS);

    hipMemsetAsync(gcursor, 0, NBUCK * sizeof(int), stream);
    partition_kernel<<<(N_EDGES + EPB - 1) / EPB, 512, 0, stream>>>(ei, gcursor, ebuf);
    bucketsort_kernel<<<NBUCK, 1024, 0, stream>>>(gcursor, ebuf, rowStart, rowEnd, dinv, x, xsb);
    fused_kernel<<<(N_NODES + 15) / 16, 256, 0, stream>>>(xsb, rowStart, rowEnd, ebuf, dinv, W1, b1, W2, zs);
    agg2_kernel<<<(N_NODES + 15) / 16, 256, 0, stream>>>(zs, rowStart, rowEnd, ebuf, dinv, b2, out);
}